// Round 5
// baseline (189.264 us; speedup 1.0000x reference)
//
#include <hip/hip_runtime.h>
#include <hip/hip_bf16.h>
#include <math.h>

#define NB 64
#define HH 512
#define WW 512
#define KK 31
#define PP 15
#define NROWS (NB * HH)         // 32768 rows total
#define ROWS_PER_WAVE 8

typedef _Float16 f16;
typedef f16 f16x8 __attribute__((ext_vector_type(8)));
typedef f16 f16x4 __attribute__((ext_vector_type(4)));

// ws layout (fast path):
//   part[0..511]     = per-block inter   (512 pass-2 blocks)
//   part[512..1023]  = per-block union
//   H (fp16) at byte offset 8192: 32 MB horizontal box-sum field
#define WS_NEED (8192 + (size_t)NROWS * WW * 2)

// ---------------- Pass 1: H(r,x) = sum_{c=x-15..x+15} mask[r][c] (zero-pad), fp16 out ----
__global__ __launch_bounds__(256) void hrow_kernel(const float* __restrict__ mask,
                                                   f16* __restrict__ H) {
    const int gw   = (blockIdx.x * 256 + threadIdx.x) >> 6;   // global wave id, 0..4095
    const int lane = threadIdx.x & 63;

    for (int k = 0; k < ROWS_PER_WAVE; ++k) {
        const size_t r = (size_t)gw * ROWS_PER_WAVE + k;
        const float* row = mask + r * WW;
        const int xbase = lane * 8;
        const float4 a = *(const float4*)(row + xbase);
        const float4 b = *(const float4*)(row + xbase + 4);

        // in-lane inclusive prefix of 8 elements
        float s0 = a.x;
        float s1 = s0 + a.y;
        float s2 = s1 + a.z;
        float s3 = s2 + a.w;
        float s4 = s3 + b.x;
        float s5 = s4 + b.y;
        float s6 = s5 + b.z;
        float s7 = s6 + b.w;

        // wave-inclusive scan of lane totals
        float incl = s7;
        #pragma unroll
        for (int off = 1; off < 64; off <<= 1) {
            float t = __shfl_up(incl, off);
            if (lane >= off) incl += t;
        }
        const float base = incl - s7;          // exclusive prefix
        s0 += base; s1 += base; s2 += base; s3 += base;
        s4 += base; s5 += base; s6 += base; s7 += base;
        // s_j = M[8*lane + j] (inclusive row prefix)

        const float total = __shfl(incl, 63);  // M[511]

        // hi taps: M[x+15]. x=8l+j: j=0 -> lane+1 elem7; j>=1 -> lane+2 elem j-1
        float hiv[8], lov[8];
        hiv[0] = __shfl_down(s7, 1);
        hiv[1] = __shfl_down(s0, 2);
        hiv[2] = __shfl_down(s1, 2);
        hiv[3] = __shfl_down(s2, 2);
        hiv[4] = __shfl_down(s3, 2);
        hiv[5] = __shfl_down(s4, 2);
        hiv[6] = __shfl_down(s5, 2);
        hiv[7] = __shfl_down(s6, 2);
        // lo taps: M[x-16] -> lane-2 elem j
        lov[0] = __shfl_up(s0, 2);
        lov[1] = __shfl_up(s1, 2);
        lov[2] = __shfl_up(s2, 2);
        lov[3] = __shfl_up(s3, 2);
        lov[4] = __shfl_up(s4, 2);
        lov[5] = __shfl_up(s5, 2);
        lov[6] = __shfl_up(s6, 2);
        lov[7] = __shfl_up(s7, 2);

        f16x8 hv;
        #pragma unroll
        for (int j = 0; j < 8; ++j) {
            const int x = xbase + j;
            const float mhi = (x + PP > WW - 1) ? total : hiv[j];
            const float mlo = (x - PP - 1 >= 0) ? lov[j] : 0.0f;
            hv[j] = (f16)(mhi - mlo);
        }
        *(f16x8*)(H + r * WW + xbase) = hv;
    }
}

// ---------------- Pass 2: running vertical 31-sum of H + fused epilogue, float4/thread ----
__device__ inline float4 loadH4(const f16* p) {
    const f16x4 v = *(const f16x4*)p;
    return make_float4((float)v[0], (float)v[1], (float)v[2], (float)v[3]);
}

__global__ __launch_bounds__(256) void dice_kernel(
        const float* __restrict__ pred,
        const float* __restrict__ mask,
        const f16* __restrict__ H,
        float* __restrict__ part) {
    const int bx   = blockIdx.x;            // 0..7  (pair of 32-row strips)
    const int b    = blockIdx.y;
    const int t    = threadIdx.x;
    const int g    = t >> 7;                // 0/1: which 32-row strip
    const int q    = t & 127;               // column group
    const int c    = q * 4;                 // first of 4 columns
    const int wave = t >> 6;
    const int lane = t & 63;

    __shared__ float red[8];

    const f16*   Hb = H    + (size_t)b * HH * WW;
    const float* mb = mask + (size_t)b * HH * WW;
    const float* pb = pred + (size_t)b * HH * WW;
    const int y0 = (bx * 2 + g) * 32;

    // init: B = sum_{r=y0-15}^{y0+14} H[r][c..c+3] (rows clamped to >=0)
    float4 B = make_float4(0.f, 0.f, 0.f, 0.f);
    {
        const int rlo = (y0 - PP < 0) ? 0 : y0 - PP;
        const int rhi = y0 + PP - 1;        // always < HH
        for (int r = rlo; r <= rhi; ++r) {
            const float4 h = loadH4(Hb + (size_t)r * WW + c);
            B.x += h.x; B.y += h.y; B.z += h.z; B.w += h.w;
        }
    }

    float4 inter4 = make_float4(0.f, 0.f, 0.f, 0.f);
    float4 uni4   = make_float4(0.f, 0.f, 0.f, 0.f);
    const float4 zero4 = make_float4(0.f, 0.f, 0.f, 0.f);
    const float inv2 = 1.0f / (float)(KK * KK);

    #pragma unroll 4
    for (int i = 0; i < 32; ++i) {
        const int y = y0 + i;
        const float4 he = (y + PP < HH) ? loadH4(Hb + (size_t)(y + PP) * WW + c) : zero4;
        const float4 hl = (y - PP >= 0) ? loadH4(Hb + (size_t)(y - PP) * WW + c) : zero4;
        const float4 m  = *(const float4*)(mb + (size_t)y * WW + c);
        const float4 p  = *(const float4*)(pb + (size_t)y * WW + c);

        B.x += he.x; B.y += he.y; B.z += he.z; B.w += he.w;

        const float w0 = 1.0f + 5.0f * fabsf(B.x * inv2 - m.x);
        const float w1 = 1.0f + 5.0f * fabsf(B.y * inv2 - m.y);
        const float w2 = 1.0f + 5.0f * fabsf(B.z * inv2 - m.z);
        const float w3 = 1.0f + 5.0f * fabsf(B.w * inv2 - m.w);
        const float sg0 = 1.0f / (1.0f + __expf(-p.x));
        const float sg1 = 1.0f / (1.0f + __expf(-p.y));
        const float sg2 = 1.0f / (1.0f + __expf(-p.z));
        const float sg3 = 1.0f / (1.0f + __expf(-p.w));

        inter4.x += sg0 * m.x * w0;  uni4.x += (sg0 + m.x) * w0;
        inter4.y += sg1 * m.y * w1;  uni4.y += (sg1 + m.y) * w1;
        inter4.z += sg2 * m.z * w2;  uni4.z += (sg2 + m.z) * w2;
        inter4.w += sg3 * m.w * w3;  uni4.w += (sg3 + m.w) * w3;

        B.x -= hl.x; B.y -= hl.y; B.z -= hl.z; B.w -= hl.w;
    }

    float inter = inter4.x + inter4.y + inter4.z + inter4.w;
    float uni   = uni4.x + uni4.y + uni4.z + uni4.w;
    #pragma unroll
    for (int off = 32; off > 0; off >>= 1) {
        inter += __shfl_down(inter, off);
        uni   += __shfl_down(uni, off);
    }
    if (lane == 0) { red[wave] = inter; red[4 + wave] = uni; }
    __syncthreads();
    if (t == 0) {
        const float ti = red[0] + red[1] + red[2] + red[3];
        const float tu = red[4] + red[5] + red[6] + red[7];
        const int bid = b * 8 + bx;
        part[bid]       = ti;
        part[512 + bid] = tu;
    }
}

// ---------------- Fallback (round-3 monolithic) if ws too small ---------------
#define NSTRIP 16
#define SROWS (HH / NSTRIP)
#define RPB 4
#define NROUND (SROWS / RPB)
#define PSTR 544

__global__ __launch_bounds__(512, 8) void dice_strip_kernel(
        const float* __restrict__ pred,
        const float* __restrict__ mask,
        float* __restrict__ part) {
    const int strip = blockIdx.x;
    const int b     = blockIdx.y;
    const int x     = threadIdx.x;
    const int wave  = x >> 6;
    const int lane  = x & 63;

    __shared__ float wtot[RPB * 8];
    __shared__ float Pbuf[RPB * PSTR];
    __shared__ float red[16];

    const float* mbase = mask + (size_t)b * HH * WW;
    const float* pbase = pred + (size_t)b * HH * WW;
    const int y0 = strip * SROWS;

    if (x < 16) {
        #pragma unroll
        for (int r = 0; r < RPB; ++r) Pbuf[r * PSTR + x] = 0.0f;
    }
    float vcarry = 0.0f;
    {
        const int rlo = (y0 - PP - 1 < 0) ? 0 : y0 - PP - 1;
        const int rhi = (y0 + PP - 1 > HH - 1) ? HH - 1 : y0 + PP - 1;
        for (int r = rlo; r <= rhi; ++r) vcarry += mbase[r * WW + x];
    }
    float inter = 0.0f, uni = 0.0f;
    for (int j = 0; j < NROUND; ++j) {
        const int y = y0 + j * RPB;
        float en[RPB], lv[RPB], mc[RPB], pv[RPB];
        #pragma unroll
        for (int r = 0; r < RPB; ++r) {
            const int ra = y + r + PP;
            const int rs = y + r - PP - 1;
            en[r] = (ra < HH) ? mbase[ra * WW + x] : 0.0f;
            lv[r] = (rs >= 0) ? mbase[rs * WW + x] : 0.0f;
            mc[r] = mbase[(y + r) * WW + x];
            pv[r] = pbase[(y + r) * WW + x];
        }
        float incl[RPB];
        {
            float run = vcarry;
            #pragma unroll
            for (int r = 0; r < RPB; ++r) { run += en[r] - lv[r]; incl[r] = run; }
            vcarry = run;
        }
        #pragma unroll
        for (int off = 1; off < 64; off <<= 1) {
            float tt[RPB];
            #pragma unroll
            for (int r = 0; r < RPB; ++r) tt[r] = __shfl_up(incl[r], off);
            #pragma unroll
            for (int r = 0; r < RPB; ++r) if (lane >= off) incl[r] += tt[r];
        }
        if (lane == 63) {
            #pragma unroll
            for (int r = 0; r < RPB; ++r) wtot[r * 8 + wave] = incl[r];
        }
        __syncthreads();
        float bm[RPB];
        #pragma unroll
        for (int r = 0; r < RPB; ++r) bm[r] = (lane < wave) ? wtot[r * 8 + lane] : 0.0f;
        #pragma unroll
        for (int off = 1; off < 64; off <<= 1) {
            #pragma unroll
            for (int r = 0; r < RPB; ++r) bm[r] += __shfl_xor(bm[r], off);
        }
        #pragma unroll
        for (int r = 0; r < RPB; ++r) Pbuf[r * PSTR + 16 + x] = bm[r] + incl[r];
        if (wave == 7) {
            #pragma unroll
            for (int r = 0; r < RPB; ++r) {
                const float p511 = bm[r] + wtot[r * 8 + 7];
                if (lane >= 48) Pbuf[r * PSTR + 528 + (lane - 48)] = p511;
            }
        }
        __syncthreads();
        #pragma unroll
        for (int r = 0; r < RPB; ++r) {
            const float hsum = Pbuf[r * PSTR + 16 + x + PP] - Pbuf[r * PSTR + x];
            const float avg  = hsum * (1.0f / (float)(KK * KK));
            const float m    = mc[r];
            const float w    = 1.0f + 5.0f * fabsf(avg - m);
            const float sg   = 1.0f / (1.0f + __expf(-pv[r]));
            inter += sg * m * w;
            uni   += (sg + m) * w;
        }
    }
    #pragma unroll
    for (int off = 32; off > 0; off >>= 1) {
        inter += __shfl_down(inter, off);
        uni   += __shfl_down(uni, off);
    }
    if (lane == 0) { red[wave] = inter; red[8 + wave] = uni; }
    __syncthreads();
    if (x == 0) {
        float ti = 0.0f, tu = 0.0f;
        #pragma unroll
        for (int w2 = 0; w2 < 8; ++w2) { ti += red[w2]; tu += red[8 + w2]; }
        const int bid = b * NSTRIP + strip;
        part[bid] = ti;
        part[NB * NSTRIP + bid] = tu;
    }
}

// ---------------- Final reduction ---------------
__global__ void dice_final_kernel(const float* __restrict__ part,
                                  float* __restrict__ out, int nper, int stride) {
    const int t = threadIdx.x;  // 64 threads, one per image
    float inter = 0.0f, uni = 0.0f;
    for (int s = 0; s < nper; ++s) {
        inter += part[t * nper + s];
        uni   += part[stride + t * nper + s];
    }
    float wd = 1.0f - (2.0f * inter + 0.5f) / (uni + 0.5f);
    #pragma unroll
    for (int off = 32; off > 0; off >>= 1) wd += __shfl_down(wd, off);
    if (t == 0) out[0] = wd * (1.0f / (float)NB);
}

extern "C" void kernel_launch(void* const* d_in, const int* in_sizes, int n_in,
                              void* d_out, int out_size, void* d_ws, size_t ws_size,
                              hipStream_t stream) {
    const float* pred = (const float*)d_in[0];
    const float* mask = (const float*)d_in[1];
    float* out  = (float*)d_out;
    float* part = (float*)d_ws;
    f16*   H    = (f16*)((char*)d_ws + 8192);

    if (ws_size >= WS_NEED) {
        hrow_kernel<<<1024, 256, 0, stream>>>(mask, H);
        dim3 grid2(8, NB);               // 512 blocks, 2 strips each
        dice_kernel<<<grid2, 256, 0, stream>>>(pred, mask, H, part);
        dice_final_kernel<<<1, 64, 0, stream>>>(part, out, 8, 512);
    } else {
        dim3 grid2(NSTRIP, NB);
        dice_strip_kernel<<<grid2, 512, 0, stream>>>(pred, mask, part);
        dice_final_kernel<<<1, 64, 0, stream>>>(part, out, NSTRIP, NB * NSTRIP);
    }
}